// Round 4
// baseline (77467.102 us; speedup 1.0000x reference)
//
#include <hip/hip_runtime.h>
#include <math.h>

// LSTM T=32768, B=1, I=128, H=512. Persistent kernel: 32 team WGs x 512 threads.
// R16 = R15 (XCD0 team via bid%8, fast rail = plain store -> XCD-local L2 +
// sc0 polls, slow rail = sc1/MALL mirror for escalation) + CRITICAL-PATH FIX:
//   * R15 regression diagnosed: wave0 (the poller) also issued the sc1 mirror
//     store; its next poll's s_waitcnt vmcnt(0) had to drain that MALL store
//     (~400-900 cy) EVERY step — re-adding the exact latency the fast rail
//     removed. FETCH collapse (355->52 MB) proved the L2 rail worked; the
//     drain explains why it didn't get faster.
//   * Fix 1: mirror store moved to a ROTATING compute wave (wv = 1 + t%7),
//     read from gather_lds after barrier B. Wave0's vmcnt now only covers
//     L2-ack'd fast stores + sc0 poll loads. Amortized mirror stall ~30ns/step.
//   * Fix 2: s_sleep(1) after each failed poll ballot — damps the 32-wave
//     reader storm on the 32 hot L2 lines (adds <=~100ns detect latency).
//   * Fix 3: escalation hardened (ft 96->512, strikes 3->8) so scheduler
//     jitter can't flip a healthy run into sticky slowMode.
// Wire format (8-bit in-band tag), t=0 zero-synthesis, coalesced publish,
// compute datapath: unchanged from R15 (verified absmax 3.05e-5).

#define T_SEQ 32768
#define HID   512
#define INP   128
#define NWG   32    // team size
#define GRID  256   // launched WGs; team = bids {0,8,...,248} -> XCD0
#define NTH   512   // 8 waves; wave0 polls then computes
#define HSL   16    // h elements per WG
#define KW    64    // W_hh weights per thread
#define KX    16    // W_ih weights per thread
#define NPK   256   // packets per parity (2 h each)

typedef unsigned long long u64;
typedef unsigned int u32;

__device__ __forceinline__ float fast_sigmoid(float x) {
    return 1.0f / (1.0f + __expf(-x));
}
__device__ __forceinline__ float fast_tanh(float x) {
    float a = fabsf(x);
    float e = __expf(-2.0f * a);          // underflows to 0 for large a -> r=1
    float r = (1.0f - e) / (1.0f + e);
    return copysignf(r, x);
}

__global__ void __launch_bounds__(NTH, 1) lstm_persist(
    const float* __restrict__ x,
    const float* __restrict__ W_ih,
    const float* __restrict__ W_hh,
    const float* __restrict__ b_ih,
    const float* __restrict__ b_hh,
    const float* __restrict__ W1,
    const float* __restrict__ b1,
    const float* __restrict__ Wout,
    u64* __restrict__ hb_fast,          // 2 x 256 packets (XCD-local rail)
    u64* __restrict__ hb_slow,          // 2 x 256 packets (MALL rail)
    float* __restrict__ out)
{
    const int bid = blockIdx.x;
    if (bid & 7) return;                // team: one block per XCD0 CU
    const int w   = bid >> 3;           // team slot 0..31
    const int tid = threadIdx.x;
    const int wv  = tid >> 6;           // 0..7
    const int l   = tid & 63;
    const int rw  = l >> 3;             // 0..7 = (gate g, elem b)
    const int j   = l & 7;              // K-chunk
    const int g   = rw >> 1;
    const int b   = rw & 1;
    const bool is_out = (w == 0 && wv == 1);   // slot0 wave1 computes out[]

    __shared__ __align__(16) float h_lds[2][HID];   // parity double buffer
    __shared__ u64 gather_lds[8];                   // per-wave packet staging

    // each wave owns elements {16w + 2wv, 16w + 2wv + 1}; 8 rows (4 gates x 2)
    const int grow = g * HID + w * HSL + 2 * wv + b;

    // ---- weights, j-rotated order to match the LDS read schedule ----
    float wr[KW], wi[KX];
#pragma unroll
    for (int kk = 0; kk < 16; ++kk) {
        const int p = (kk + 2 * j) & 15;
        const float4 v4 = *(const float4*)&W_hh[grow * HID + j * KW + 4 * p];
        wr[4 * kk + 0] = v4.x; wr[4 * kk + 1] = v4.y;
        wr[4 * kk + 2] = v4.z; wr[4 * kk + 3] = v4.w;
    }
#pragma unroll
    for (int k = 0; k < KX; k += 4) {
        const float4 v4 = *(const float4*)&W_ih[grow * INP + j * KX + k];
        wi[k] = v4.x; wi[k + 1] = v4.y; wi[k + 2] = v4.z; wi[k + 3] = v4.w;
    }
    float brow = b_ih[grow] + b_hh[grow];

    // out-projection weights (slot0 wave1): lane l covers h indices l + 64*i
    float weff_o[8];
    float be = 0.0f;
#pragma unroll
    for (int i = 0; i < 8; ++i) weff_o[i] = 0.0f;
    if (is_out) {
#pragma unroll
        for (int i = 0; i < 8; ++i) {
            float s = 0.0f;
            for (int p = 0; p < 25; ++p) s += Wout[p] * W1[p * HID + l + 64 * i];
            weff_o[i] = s;
        }
        for (int p = 0; p < 25; ++p) be += b1[p] * Wout[p];
    }
    // pin against in-loop memory clobbers
#pragma unroll
    for (int k = 0; k < KW; ++k) asm volatile("" : "+v"(wr[k]));
#pragma unroll
    for (int k = 0; k < KX; ++k) asm volatile("" : "+v"(wi[k]));
#pragma unroll
    for (int i = 0; i < 8; ++i) asm volatile("" : "+v"(weff_o[i]));
    asm volatile("" : "+v"(brow));
    asm volatile("" : "+v"(be));

    float c = 0.0f;
    float xa[KX];
#pragma unroll
    for (int k = 0; k < KX; ++k) xa[k] = x[j * KX + k];

    bool dead = false;        // safety latch: never hang the device
    bool slowMode = false;    // sticky: fast rail declared dead
    int  slowSteps = 0;       // escalated-step count (t>=4 only)

    for (u32 t = 0; t <= T_SEQ; ++t) {
        if (t == T_SEQ && w != 0) break;   // only slot0 runs the tail iteration

        // ---- x-dot partials for step t (pure VALU; overlaps the poll) ----
        float xd0 = 0.0f, xd1 = 0.0f, xd2 = 0.0f, xd3 = 0.0f;
#pragma unroll
        for (int k = 0; k < KX; k += 4) {
            xd0 += wi[k + 0] * xa[k + 0];
            xd1 += wi[k + 1] * xa[k + 1];
            xd2 += wi[k + 2] * xa[k + 2];
            xd3 += wi[k + 3] * xa[k + 3];
        }
        // xa consumed -> prefetch x_{t+1}. Compute waves: before the barrier
        // (latency hides inside the wait). Poller: after the barrier.
        const int tn = (t + 1 < T_SEQ) ? (int)(t + 1) : (T_SEQ - 1);
        if (wv != 0) {
#pragma unroll
            for (int k = 0; k < KX; k += 4) {
                const float4 x4 = *(const float4*)&x[tn * INP + j * KX + k];
                xa[k + 0] = x4.x; xa[k + 1] = x4.y;
                xa[k + 2] = x4.z; xa[k + 3] = x4.w;
            }
        }

        // ---- wave0 fills h_lds: t=0 synthesizes h0=0; t>=1 polls, fast
        //      rail (sc0, XCD-local L2) with escalation to the slow rail
        //      (agent loads at MALL) ----
        if (wv == 0 && !dead) {
            float2* HL = (float2*)h_lds[t & 1];
            if (t == 0) {
                float2 z; z.x = 0.0f; z.y = 0.0f;
                HL[l +   0] = z;
                HL[l +  64] = z;
                HL[l + 128] = z;
                HL[l + 192] = z;
            } else {
                const int par = (t & 1) * NPK;
                const u64 a0 = (u64)(hb_fast + par + l);
                const u64 a1 = a0 +  64u * sizeof(u64);
                const u64 a2 = a0 + 128u * sizeof(u64);
                const u64 a3 = a0 + 192u * sizeof(u64);
                const u64* PS = hb_slow + par;
                const u32 tLo = t & 15u;
                const u32 tHi = (t >> 4) & 15u;
                const int ft = (t < 4) ? 8192 : 512;   // escalation threshold
                bool mine = false;
                bool slow = slowMode;
                int it = 0;
                while (true) {
                    if (!mine) {
                        u64 p0, p1, p2, p3;
                        if (!slow) {
                            asm volatile(
                                "global_load_dwordx2 %0, %4, off sc0\n\t"
                                "global_load_dwordx2 %1, %5, off sc0\n\t"
                                "global_load_dwordx2 %2, %6, off sc0\n\t"
                                "global_load_dwordx2 %3, %7, off sc0\n\t"
                                "s_waitcnt vmcnt(0)"
                                : "=&v"(p0), "=&v"(p1), "=&v"(p2), "=&v"(p3)
                                : "v"(a0), "v"(a1), "v"(a2), "v"(a3)
                                : "memory");
                            __builtin_amdgcn_sched_barrier(0);
                        } else {
                            p0 = __hip_atomic_load(PS + l, __ATOMIC_RELAXED,
                                                   __HIP_MEMORY_SCOPE_AGENT);
                            p1 = __hip_atomic_load(PS + l + 64, __ATOMIC_RELAXED,
                                                   __HIP_MEMORY_SCOPE_AGENT);
                            p2 = __hip_atomic_load(PS + l + 128, __ATOMIC_RELAXED,
                                                   __HIP_MEMORY_SCOPE_AGENT);
                            p3 = __hip_atomic_load(PS + l + 192, __ATOMIC_RELAXED,
                                                   __HIP_MEMORY_SCOPE_AGENT);
                        }
                        const bool ok =
                            ((((u32)p0 ^ tLo) & 15u) == 0u) &&
                            ((((u32)(p0 >> 32) ^ tHi) & 15u) == 0u) &&
                            ((((u32)p1 ^ tLo) & 15u) == 0u) &&
                            ((((u32)(p1 >> 32) ^ tHi) & 15u) == 0u) &&
                            ((((u32)p2 ^ tLo) & 15u) == 0u) &&
                            ((((u32)(p2 >> 32) ^ tHi) & 15u) == 0u) &&
                            ((((u32)p3 ^ tLo) & 15u) == 0u) &&
                            ((((u32)(p3 >> 32) ^ tHi) & 15u) == 0u);
                        if (ok) {
                            float2 h0, h1, h2, h3;
                            h0.x = __uint_as_float((u32)p0);
                            h0.y = __uint_as_float((u32)(p0 >> 32));
                            h1.x = __uint_as_float((u32)p1);
                            h1.y = __uint_as_float((u32)(p1 >> 32));
                            h2.x = __uint_as_float((u32)p2);
                            h2.y = __uint_as_float((u32)(p2 >> 32));
                            h3.x = __uint_as_float((u32)p3);
                            h3.y = __uint_as_float((u32)(p3 >> 32));
                            HL[l +   0] = h0;
                            HL[l +  64] = h1;
                            HL[l + 128] = h2;
                            HL[l + 192] = h3;
                            mine = true;
                        }
                    }
                    if (__ballot(mine) == ~0ull) break;
                    __builtin_amdgcn_s_sleep(1);   // damp the reader storm
                    ++it;
                    if (it == ft) slow = true;                 // escalate step
                    if (it > (1 << 22)) { dead = true; break; }   // no hang
                }
                if (slow && !slowMode && t >= 4) {
                    if (++slowSteps >= 8) slowMode = true;     // sticky
                }
            }
        }
        __syncthreads();

        if (t < T_SEQ) {
            float a0 = xd0, a1 = xd1, a2 = xd2, a3 = xd3;
            const float4* hl4 = (const float4*)&h_lds[t & 1][j * KW];
#pragma unroll
            for (int kk = 0; kk < 16; ++kk) {
                const int p = (kk + 2 * j) & 15;
                const float4 h4 = hl4[p];
                a0 += wr[4 * kk + 0] * h4.x;
                a1 += wr[4 * kk + 1] * h4.y;
                a2 += wr[4 * kk + 2] * h4.z;
                a3 += wr[4 * kk + 3] * h4.w;
            }
            // poller's x-prefetch (after barrier, overlaps the h-dot)
            if (wv == 0) {
#pragma unroll
                for (int k = 0; k < KX; k += 4) {
                    const float4 x4 = *(const float4*)&x[tn * INP + j * KX + k];
                    xa[k + 0] = x4.x; xa[k + 1] = x4.y;
                    xa[k + 2] = x4.z; xa[k + 3] = x4.w;
                }
            }
            // xor-butterfly over j: every lane holds its row's full sum
            float acc = (a0 + a1) + (a2 + a3);
            acc += __shfl_xor(acc, 1);
            acc += __shfl_xor(acc, 2);
            acc += __shfl_xor(acc, 4);
            acc += brow;
            // gates of element b live at rw = b, b+2, b+4, b+6 (valid l<16)
            const float ig = acc;
            const float fg = __shfl(acc, l + 16);
            const float gg = __shfl(acc, l + 32);
            const float og = __shfl(acc, l + 48);
            const float iv = fast_sigmoid(ig);
            const float fv = fast_sigmoid(fg);
            const float gv = fast_tanh(gg);
            const float ov = fast_sigmoid(og);
            c = fv * c + iv * gv;
            const float hv = ov * fast_tanh(c);
            // stage this wave's packet: 8-bit tag in-band — (t+1)&15 in
            // h_even low nibble, ((t+1)>>4)&15 in h_odd low nibble
            const float hv1 = __shfl(hv, 8);     // element b=1 (lane 8)
            if (l == 0) {
                const u32 b0  = (__float_as_uint(hv)  & ~15u) | ((t + 1) & 15u);
                const u32 b1v = (__float_as_uint(hv1) & ~15u) | (((t + 1) >> 4) & 15u);
                gather_lds[wv] = ((u64)b1v << 32) | (u64)b0;
            }
            __syncthreads();   // barrier B: all 8 packets staged
            // ---- dual-rail coalesced publish, split across waves:
            //   wave0 lanes 0-7: fast rail (plain stores -> XCD-local L2).
            //   rotating compute wave (1 + t%7) lanes 0-7: sc1 mirror to the
            //   slow rail. Keeps the MALL store drain OFF wave0's vmcnt path
            //   (the R15 regression); each compute wave pays it 1/7 of steps.
            const int mwv = 1 + (int)(t % 7u);
            if (wv == 0 && l < 8) {
                const u64 pkt = gather_lds[l];
                const u64 adf = (u64)&hb_fast[((t + 1) & 1) * NPK + w * 8 + l];
                asm volatile("global_store_dwordx2 %0, %1, off"
                             :: "v"(adf), "v"(pkt) : "memory");
            } else if (wv == mwv && l < 8) {
                const u64 pkt = gather_lds[l];
                __hip_atomic_store(&hb_slow[((t + 1) & 1) * NPK + w * 8 + l],
                                   pkt, __ATOMIC_RELAXED,
                                   __HIP_MEMORY_SCOPE_AGENT);
            }
        }

        // out[t-1] = dot(h_{t-1}, w_eff) + b_eff — slot0 wave1, after publish
        if (is_out && t >= 1) {
            float pd = 0.0f;
#pragma unroll
            for (int i = 0; i < 8; ++i)
                pd += h_lds[t & 1][l + 64 * i] * weff_o[i];
            pd += __shfl_xor(pd, 1);
            pd += __shfl_xor(pd, 2);
            pd += __shfl_xor(pd, 4);
            pd += __shfl_xor(pd, 8);
            pd += __shfl_xor(pd, 16);
            pd += __shfl_xor(pd, 32);
            if (l == 0) out[t - 1] = pd + be;
        }
    }
}

extern "C" void kernel_launch(void* const* d_in, const int* in_sizes, int n_in,
                              void* d_out, int out_size, void* d_ws, size_t ws_size,
                              hipStream_t stream)
{
    const float* x    = (const float*)d_in[0];
    const float* W_ih = (const float*)d_in[1];
    const float* W_hh = (const float*)d_in[2];
    const float* b_ih = (const float*)d_in[3];
    const float* b_hh = (const float*)d_in[4];
    const float* W1   = (const float*)d_in[5];
    const float* b1   = (const float*)d_in[6];
    const float* Wout = (const float*)d_in[7];
    float* out = (float*)d_out;

    u64* hb_fast = (u64*)d_ws;              // 2 x 256 packets = 4 KB
    u64* hb_slow = hb_fast + 2 * NPK;       // 2 x 256 packets = 4 KB

    // zero both rails (tags reject stale data; t=0 never reads the wire)
    hipMemsetAsync(d_ws, 0, 4 * NPK * sizeof(u64), stream);
    lstm_persist<<<GRID, NTH, 0, stream>>>(x, W_ih, W_hh, b_ih, b_hh, W1, b1,
                                           Wout, hb_fast, hb_slow, out);
}

// Round 6
// 76795.490 us; speedup vs baseline: 1.0087x; 1.0087x over previous
//
#include <hip/hip_runtime.h>
#include <math.h>

// LSTM T=32768, B=1, I=128, H=512. Persistent kernel: 32 team WGs x 512 threads.
// R18 = R16 (verified: XCD0 team via bid%8, fast rail = plain store -> XCD-
// local L2 + sc0 polls, slow rail = sc1/MALL mirror by rotating wave issued
// post-barrier-B i.e. BEFORE the WG's own next poll => deadlock-free) + the
// MINIMAL barrier-drain fix:
//   * DIAGNOSIS (R12/R15/R16 all ~2.0-2.3us/step): __syncthreads lowers to
//     s_waitcnt vmcnt(0) lgkmcnt(0); s_barrier. Every step the rendezvous
//     drains (a) compute waves' 4-load HBM x-prefetch (~700-900cy) and (b) the
//     mirror wave's sc1 MALL store. Barrier release = max(arrivals) => the
//     step is floored by HBM/MALL retire latency no matter how fast the
//     (proven-live, FETCH 355->52MB) L2 packet rail is.
//   * R17's attempt at this failed from a SELF-DEADLOCK: it moved the mirror
//     to after barrier A, so a sticky-slowMode WG waited on its own mirror
//     that only its own post-poll code could issue. R18 keeps R16's mirror
//     placement (issued before the WG's next poll) and ONLY swaps barriers.
//   * Change 1: both in-loop __syncthreads -> lgkm-only barrier
//     (s_waitcnt lgkmcnt(0); s_barrier). LDS orderings (h_lds, gather_lds)
//     are lgkm-covered; global prefetch + sc1 mirror fly across the barrier
//     (proven pattern: 8-phase GEMM template, m218). Compiler still inserts
//     waits before each loaded value's USE, a full step later => hidden.
//   * Change 2: s_sleep(1) removed (R16's measured regression vs R15).
// Wire format (8-bit in-band tag), t=0 zero-synthesis, escalation fallback,
// coalesced publish, compute datapath: byte-identical to R16 (absmax 3.05e-5).

#define T_SEQ 32768
#define HID   512
#define INP   128
#define NWG   32    // team size
#define GRID  256   // launched WGs; team = bids {0,8,...,248} -> XCD0
#define NTH   512   // 8 waves; wave0 polls then computes
#define HSL   16    // h elements per WG
#define KW    64    // W_hh weights per thread
#define KX    16    // W_ih weights per thread
#define NPK   256   // packets per parity (2 h each)

typedef unsigned long long u64;
typedef unsigned int u32;

__device__ __forceinline__ float fast_sigmoid(float x) {
    return 1.0f / (1.0f + __expf(-x));
}
__device__ __forceinline__ float fast_tanh(float x) {
    float a = fabsf(x);
    float e = __expf(-2.0f * a);          // underflows to 0 for large a -> r=1
    float r = (1.0f - e) / (1.0f + e);
    return copysignf(r, x);
}

// Workgroup rendezvous draining ONLY lgkmcnt (LDS). vmcnt (global loads &
// stores) stays in flight across it — the whole point of R18. sched_barrier
// pins codegen around the asm (guide rule #18).
__device__ __forceinline__ void wg_barrier_lgkm() {
    __builtin_amdgcn_sched_barrier(0);
    asm volatile("s_waitcnt lgkmcnt(0)" ::: "memory");
    __builtin_amdgcn_s_barrier();
    __builtin_amdgcn_sched_barrier(0);
}

__global__ void __launch_bounds__(NTH, 1) lstm_persist(
    const float* __restrict__ x,
    const float* __restrict__ W_ih,
    const float* __restrict__ W_hh,
    const float* __restrict__ b_ih,
    const float* __restrict__ b_hh,
    const float* __restrict__ W1,
    const float* __restrict__ b1,
    const float* __restrict__ Wout,
    u64* __restrict__ hb_fast,          // 2 x 256 packets (XCD-local rail)
    u64* __restrict__ hb_slow,          // 2 x 256 packets (MALL rail)
    float* __restrict__ out)
{
    const int bid = blockIdx.x;
    if (bid & 7) return;                // team: one block per XCD0 CU
    const int w   = bid >> 3;           // team slot 0..31
    const int tid = threadIdx.x;
    const int wv  = tid >> 6;           // 0..7
    const int l   = tid & 63;
    const int rw  = l >> 3;             // 0..7 = (gate g, elem b)
    const int j   = l & 7;              // K-chunk
    const int g   = rw >> 1;
    const int b   = rw & 1;
    const bool is_out = (w == 0 && wv == 1);   // slot0 wave1 computes out[]

    __shared__ __align__(16) float h_lds[2][HID];   // parity double buffer
    __shared__ u64 gather_lds[8];                   // per-wave packet staging

    // each wave owns elements {16w + 2wv, 16w + 2wv + 1}; 8 rows (4 gates x 2)
    const int grow = g * HID + w * HSL + 2 * wv + b;

    // ---- weights, j-rotated order to match the LDS read schedule ----
    float wr[KW], wi[KX];
#pragma unroll
    for (int kk = 0; kk < 16; ++kk) {
        const int p = (kk + 2 * j) & 15;
        const float4 v4 = *(const float4*)&W_hh[grow * HID + j * KW + 4 * p];
        wr[4 * kk + 0] = v4.x; wr[4 * kk + 1] = v4.y;
        wr[4 * kk + 2] = v4.z; wr[4 * kk + 3] = v4.w;
    }
#pragma unroll
    for (int k = 0; k < KX; k += 4) {
        const float4 v4 = *(const float4*)&W_ih[grow * INP + j * KX + k];
        wi[k] = v4.x; wi[k + 1] = v4.y; wi[k + 2] = v4.z; wi[k + 3] = v4.w;
    }
    float brow = b_ih[grow] + b_hh[grow];

    // out-projection weights (slot0 wave1): lane l covers h indices l + 64*i
    float weff_o[8];
    float be = 0.0f;
#pragma unroll
    for (int i = 0; i < 8; ++i) weff_o[i] = 0.0f;
    if (is_out) {
#pragma unroll
        for (int i = 0; i < 8; ++i) {
            float s = 0.0f;
            for (int p = 0; p < 25; ++p) s += Wout[p] * W1[p * HID + l + 64 * i];
            weff_o[i] = s;
        }
        for (int p = 0; p < 25; ++p) be += b1[p] * Wout[p];
    }
    // pin against in-loop memory clobbers
#pragma unroll
    for (int k = 0; k < KW; ++k) asm volatile("" : "+v"(wr[k]));
#pragma unroll
    for (int k = 0; k < KX; ++k) asm volatile("" : "+v"(wi[k]));
#pragma unroll
    for (int i = 0; i < 8; ++i) asm volatile("" : "+v"(weff_o[i]));
    asm volatile("" : "+v"(brow));
    asm volatile("" : "+v"(be));

    float c = 0.0f;
    float xa[KX];
#pragma unroll
    for (int k = 0; k < KX; ++k) xa[k] = x[j * KX + k];

    bool dead = false;        // safety latch: never hang the device
    bool slowMode = false;    // sticky: fast rail declared dead
    int  slowSteps = 0;       // escalated-step count (t>=4 only)

    for (u32 t = 0; t <= T_SEQ; ++t) {
        if (t == T_SEQ && w != 0) break;   // only slot0 runs the tail iteration

        // ---- x-dot partials for step t (pure VALU; overlaps the poll) ----
        float xd0 = 0.0f, xd1 = 0.0f, xd2 = 0.0f, xd3 = 0.0f;
#pragma unroll
        for (int k = 0; k < KX; k += 4) {
            xd0 += wi[k + 0] * xa[k + 0];
            xd1 += wi[k + 1] * xa[k + 1];
            xd2 += wi[k + 2] * xa[k + 2];
            xd3 += wi[k + 3] * xa[k + 3];
        }
        // xa consumed -> prefetch x_{t+1}. Compute waves: issue now; the load
        // flies ACROSS the lgkm-only barrier (no drain) and is waited only at
        // its use next step. Poller: issues after the barrier.
        const int tn = (t + 1 < T_SEQ) ? (int)(t + 1) : (T_SEQ - 1);
        if (wv != 0) {
#pragma unroll
            for (int k = 0; k < KX; k += 4) {
                const float4 x4 = *(const float4*)&x[tn * INP + j * KX + k];
                xa[k + 0] = x4.x; xa[k + 1] = x4.y;
                xa[k + 2] = x4.z; xa[k + 3] = x4.w;
            }
        }

        // ---- wave0 fills h_lds: t=0 synthesizes h0=0; t>=1 polls, fast
        //      rail (sc0, XCD-local L2) with escalation to the slow rail
        //      (agent loads at MALL) ----
        if (wv == 0 && !dead) {
            float2* HL = (float2*)h_lds[t & 1];
            if (t == 0) {
                float2 z; z.x = 0.0f; z.y = 0.0f;
                HL[l +   0] = z;
                HL[l +  64] = z;
                HL[l + 128] = z;
                HL[l + 192] = z;
            } else {
                const int par = (t & 1) * NPK;
                const u64 a0 = (u64)(hb_fast + par + l);
                const u64 a1 = a0 +  64u * sizeof(u64);
                const u64 a2 = a0 + 128u * sizeof(u64);
                const u64 a3 = a0 + 192u * sizeof(u64);
                const u64* PS = hb_slow + par;
                const u32 tLo = t & 15u;
                const u32 tHi = (t >> 4) & 15u;
                const int ft = (t < 4) ? 8192 : 512;   // escalation threshold
                bool mine = false;
                bool slow = slowMode;
                int it = 0;
                while (true) {
                    if (!mine) {
                        u64 p0, p1, p2, p3;
                        if (!slow) {
                            asm volatile(
                                "global_load_dwordx2 %0, %4, off sc0\n\t"
                                "global_load_dwordx2 %1, %5, off sc0\n\t"
                                "global_load_dwordx2 %2, %6, off sc0\n\t"
                                "global_load_dwordx2 %3, %7, off sc0\n\t"
                                "s_waitcnt vmcnt(0)"
                                : "=&v"(p0), "=&v"(p1), "=&v"(p2), "=&v"(p3)
                                : "v"(a0), "v"(a1), "v"(a2), "v"(a3)
                                : "memory");
                            __builtin_amdgcn_sched_barrier(0);
                        } else {
                            p0 = __hip_atomic_load(PS + l, __ATOMIC_RELAXED,
                                                   __HIP_MEMORY_SCOPE_AGENT);
                            p1 = __hip_atomic_load(PS + l + 64, __ATOMIC_RELAXED,
                                                   __HIP_MEMORY_SCOPE_AGENT);
                            p2 = __hip_atomic_load(PS + l + 128, __ATOMIC_RELAXED,
                                                   __HIP_MEMORY_SCOPE_AGENT);
                            p3 = __hip_atomic_load(PS + l + 192, __ATOMIC_RELAXED,
                                                   __HIP_MEMORY_SCOPE_AGENT);
                        }
                        const bool ok =
                            ((((u32)p0 ^ tLo) & 15u) == 0u) &&
                            ((((u32)(p0 >> 32) ^ tHi) & 15u) == 0u) &&
                            ((((u32)p1 ^ tLo) & 15u) == 0u) &&
                            ((((u32)(p1 >> 32) ^ tHi) & 15u) == 0u) &&
                            ((((u32)p2 ^ tLo) & 15u) == 0u) &&
                            ((((u32)(p2 >> 32) ^ tHi) & 15u) == 0u) &&
                            ((((u32)p3 ^ tLo) & 15u) == 0u) &&
                            ((((u32)(p3 >> 32) ^ tHi) & 15u) == 0u);
                        if (ok) {
                            float2 h0, h1, h2, h3;
                            h0.x = __uint_as_float((u32)p0);
                            h0.y = __uint_as_float((u32)(p0 >> 32));
                            h1.x = __uint_as_float((u32)p1);
                            h1.y = __uint_as_float((u32)(p1 >> 32));
                            h2.x = __uint_as_float((u32)p2);
                            h2.y = __uint_as_float((u32)(p2 >> 32));
                            h3.x = __uint_as_float((u32)p3);
                            h3.y = __uint_as_float((u32)(p3 >> 32));
                            HL[l +   0] = h0;
                            HL[l +  64] = h1;
                            HL[l + 128] = h2;
                            HL[l + 192] = h3;
                            mine = true;
                        }
                    }
                    if (__ballot(mine) == ~0ull) break;
                    ++it;
                    if (it == ft) slow = true;                 // escalate step
                    if (it > (1 << 22)) { dead = true; break; }   // no hang
                }
                if (slow && !slowMode && t >= 4) {
                    if (++slowSteps >= 8) slowMode = true;     // sticky
                }
            }
        }

        wg_barrier_lgkm();   // barrier A — vmcnt NOT drained

        if (t < T_SEQ) {
            float a0 = xd0, a1 = xd1, a2 = xd2, a3 = xd3;
            const float4* hl4 = (const float4*)&h_lds[t & 1][j * KW];
#pragma unroll
            for (int kk = 0; kk < 16; ++kk) {
                const int p = (kk + 2 * j) & 15;
                const float4 h4 = hl4[p];
                a0 += wr[4 * kk + 0] * h4.x;
                a1 += wr[4 * kk + 1] * h4.y;
                a2 += wr[4 * kk + 2] * h4.z;
                a3 += wr[4 * kk + 3] * h4.w;
            }
            // poller's x-prefetch (after barrier, overlaps the h-dot; its
            // waitcnt lands a full step later in wave0's next poll asm)
            if (wv == 0) {
#pragma unroll
                for (int k = 0; k < KX; k += 4) {
                    const float4 x4 = *(const float4*)&x[tn * INP + j * KX + k];
                    xa[k + 0] = x4.x; xa[k + 1] = x4.y;
                    xa[k + 2] = x4.z; xa[k + 3] = x4.w;
                }
            }
            // xor-butterfly over j: every lane holds its row's full sum
            float acc = (a0 + a1) + (a2 + a3);
            acc += __shfl_xor(acc, 1);
            acc += __shfl_xor(acc, 2);
            acc += __shfl_xor(acc, 4);
            acc += brow;
            // gates of element b live at rw = b, b+2, b+4, b+6 (valid l<16)
            const float ig = acc;
            const float fg = __shfl(acc, l + 16);
            const float gg = __shfl(acc, l + 32);
            const float og = __shfl(acc, l + 48);
            const float iv = fast_sigmoid(ig);
            const float fv = fast_sigmoid(fg);
            const float gv = fast_tanh(gg);
            const float ov = fast_sigmoid(og);
            c = fv * c + iv * gv;
            const float hv = ov * fast_tanh(c);
            // stage this wave's packet: 8-bit tag in-band — (t+1)&15 in
            // h_even low nibble, ((t+1)>>4)&15 in h_odd low nibble
            const float hv1 = __shfl(hv, 8);     // element b=1 (lane 8)
            if (l == 0) {
                const u32 b0  = (__float_as_uint(hv)  & ~15u) | ((t + 1) & 15u);
                const u32 b1v = (__float_as_uint(hv1) & ~15u) | (((t + 1) >> 4) & 15u);
                gather_lds[wv] = ((u64)b1v << 32) | (u64)b0;
            }

            wg_barrier_lgkm();   // barrier B — all 8 packets staged (lgkm)

            // ---- dual-rail coalesced publish, split across waves:
            //   wave0 lanes 0-7: fast rail (plain stores -> XCD-local L2).
            //   rotating compute wave (1 + t%7) lanes 0-7: sc1 mirror to the
            //   slow rail. Both issued BEFORE the WG's next poll => a sticky-
            //   slow WG still receives every WG's mirrors (deadlock-free).
            //   Neither store is drained by a barrier anymore; the mirror
            //   retires in the background off every wave's critical path.
            const int mwv = 1 + (int)(t % 7u);
            if (wv == 0 && l < 8) {
                const u64 pkt = gather_lds[l];
                const u64 adf = (u64)&hb_fast[((t + 1) & 1) * NPK + w * 8 + l];
                asm volatile("global_store_dwordx2 %0, %1, off"
                             :: "v"(adf), "v"(pkt) : "memory");
            } else if (wv == mwv && l < 8) {
                const u64 pkt = gather_lds[l];
                __hip_atomic_store(&hb_slow[((t + 1) & 1) * NPK + w * 8 + l],
                                   pkt, __ATOMIC_RELAXED,
                                   __HIP_MEMORY_SCOPE_AGENT);
            }
        }

        // out[t-1] = dot(h_{t-1}, w_eff) + b_eff — slot0 wave1, after publish
        if (is_out && t >= 1) {
            float pd = 0.0f;
#pragma unroll
            for (int i = 0; i < 8; ++i)
                pd += h_lds[t & 1][l + 64 * i] * weff_o[i];
            pd += __shfl_xor(pd, 1);
            pd += __shfl_xor(pd, 2);
            pd += __shfl_xor(pd, 4);
            pd += __shfl_xor(pd, 8);
            pd += __shfl_xor(pd, 16);
            pd += __shfl_xor(pd, 32);
            if (l == 0) out[t - 1] = pd + be;
        }
    }
}

extern "C" void kernel_launch(void* const* d_in, const int* in_sizes, int n_in,
                              void* d_out, int out_size, void* d_ws, size_t ws_size,
                              hipStream_t stream)
{
    const float* x    = (const float*)d_in[0];
    const float* W_ih = (const float*)d_in[1];
    const float* W_hh = (const float*)d_in[2];
    const float* b_ih = (const float*)d_in[3];
    const float* b_hh = (const float*)d_in[4];
    const float* W1   = (const float*)d_in[5];
    const float* b1   = (const float*)d_in[6];
    const float* Wout = (const float*)d_in[7];
    float* out = (float*)d_out;

    u64* hb_fast = (u64*)d_ws;              // 2 x 256 packets = 4 KB
    u64* hb_slow = hb_fast + 2 * NPK;       // 2 x 256 packets = 4 KB

    // zero both rails (tags reject stale data; t=0 never reads the wire)
    hipMemsetAsync(d_ws, 0, 4 * NPK * sizeof(u64), stream);
    lstm_persist<<<GRID, NTH, 0, stream>>>(x, W_ih, W_hh, b_ih, b_hh, W1, b1,
                                           Wout, hb_fast, hb_slow, out);
}

// Round 8
// 76274.408 us; speedup vs baseline: 1.0156x; 1.0068x over previous
//
#include <hip/hip_runtime.h>
#include <math.h>

// LSTM T=32768, B=1, I=128, H=512. Persistent kernel: 32 WGs x 512 threads.
// R19 = R12's single-rail MALL wire (best verified: 65.5ms; agent-scope
// atomic packets, tag-in-band) with the three serial drains removed:
//   1. lgkm-only barriers (R18-verified): __syncthreads drained vmcnt(0),
//      stalling every compute wave ~700cy at the rendezvous retiring its HBM
//      x-prefetch. Now prefetches fly across barriers; waits land at USE.
//   2. publisher != poller (R16/R18-verified placement): a rotating compute
//      wave (1 + t%7) issues the 8-packet coalesced sc1 publish post-barrier-B
//      (before anyone's next poll => deadlock-free). Wave0's poll vmcnt(0)
//      now covers ONLY its own 4 poll loads — no self-drain of MALL stores.
//   3. wave0 never touches global x: wave1 stages the x row into parity-
//      buffered x_lds (two-step-ahead regs, so the ds_write never waits on a
//      fresh load); wave0 x-dots from LDS post-barrier.
//   plus: all compute waves run x two-step-ahead (xa=x(t), xn=x(t+1) in regs,
//   prefetch x(t+2)) so phase-1 never stalls on an in-flight HBM load.
// Dual-rail/escalation machinery DELETED (R15-R18: proven ~15% net cost, no
// benefit). Wire format: 8-bit in-band tag ((t&15) in h_even low nibble,
// ((t>>4)&15) in h_odd low nibble) + t=0 zero-synthesis — R15+-verified.
// Compute datapath identical to R12 (verified absmax 3.05e-5).
// (Resubmission of R19 verbatim: round 7 bench was a GPU-acquisition timeout,
// the kernel was never measured.)

#define T_SEQ 32768
#define HID   512
#define INP   128
#define NWG   32    // workgroups (grid)
#define NTH   512   // 8 waves; wave0 polls then computes
#define HSL   16    // h elements per WG
#define KW    64    // W_hh weights per thread
#define KX    16    // W_ih weights per thread
#define NPK   256   // packets per parity (2 h each)

typedef unsigned long long u64;
typedef unsigned int u32;

__device__ __forceinline__ float fast_sigmoid(float x) {
    return 1.0f / (1.0f + __expf(-x));
}
__device__ __forceinline__ float fast_tanh(float x) {
    float a = fabsf(x);
    float e = __expf(-2.0f * a);          // underflows to 0 for large a -> r=1
    float r = (1.0f - e) / (1.0f + e);
    return copysignf(r, x);
}

// Workgroup rendezvous draining ONLY lgkmcnt (LDS). vmcnt (global loads &
// stores) stays in flight across it. sched_barrier pins codegen (rule #18).
__device__ __forceinline__ void wg_barrier_lgkm() {
    __builtin_amdgcn_sched_barrier(0);
    asm volatile("s_waitcnt lgkmcnt(0)" ::: "memory");
    __builtin_amdgcn_s_barrier();
    __builtin_amdgcn_sched_barrier(0);
}

__global__ void __launch_bounds__(NTH, 1) lstm_persist(
    const float* __restrict__ x,
    const float* __restrict__ W_ih,
    const float* __restrict__ W_hh,
    const float* __restrict__ b_ih,
    const float* __restrict__ b_hh,
    const float* __restrict__ W1,
    const float* __restrict__ b1,
    const float* __restrict__ Wout,
    u64* __restrict__ hbuf,             // 2 x 256 packets (MALL rail)
    float* __restrict__ out)
{
    const int w   = blockIdx.x;         // 0..31
    const int tid = threadIdx.x;
    const int wv  = tid >> 6;           // 0..7
    const int l   = tid & 63;
    const int rw  = l >> 3;             // 0..7 = (gate g, elem b)
    const int j   = l & 7;              // K-chunk
    const int g   = rw >> 1;
    const int b   = rw & 1;
    const bool is_out = (w == 0 && wv == 2);   // WG0 wave2 computes out[]

    __shared__ __align__(16) float h_lds[2][HID];   // parity double buffer
    __shared__ __align__(16) float x_lds[2][INP];   // parity-buffered x row
    __shared__ u64 gather_lds[8];                   // per-wave packet staging

    // each wave owns elements {16w + 2wv, 16w + 2wv + 1}; 8 rows (4 gates x 2)
    const int grow = g * HID + w * HSL + 2 * wv + b;

    // ---- weights, j-rotated order to match the LDS read schedule ----
    float wr[KW], wi[KX];
#pragma unroll
    for (int kk = 0; kk < 16; ++kk) {
        const int p = (kk + 2 * j) & 15;
        const float4 v4 = *(const float4*)&W_hh[grow * HID + j * KW + 4 * p];
        wr[4 * kk + 0] = v4.x; wr[4 * kk + 1] = v4.y;
        wr[4 * kk + 2] = v4.z; wr[4 * kk + 3] = v4.w;
    }
#pragma unroll
    for (int k = 0; k < KX; k += 4) {
        const float4 v4 = *(const float4*)&W_ih[grow * INP + j * KX + k];
        wi[k] = v4.x; wi[k + 1] = v4.y; wi[k + 2] = v4.z; wi[k + 3] = v4.w;
    }
    float brow = b_ih[grow] + b_hh[grow];

    // out-projection weights (WG0 wave2): lane l covers h indices l + 64*i
    float weff_o[8];
    float be = 0.0f;
#pragma unroll
    for (int i = 0; i < 8; ++i) weff_o[i] = 0.0f;
    if (is_out) {
#pragma unroll
        for (int i = 0; i < 8; ++i) {
            float s = 0.0f;
            for (int p = 0; p < 25; ++p) s += Wout[p] * W1[p * HID + l + 64 * i];
            weff_o[i] = s;
        }
        for (int p = 0; p < 25; ++p) be += b1[p] * Wout[p];
    }
    // pin against in-loop memory clobbers
#pragma unroll
    for (int k = 0; k < KW; ++k) asm volatile("" : "+v"(wr[k]));
#pragma unroll
    for (int k = 0; k < KX; ++k) asm volatile("" : "+v"(wi[k]));
#pragma unroll
    for (int i = 0; i < 8; ++i) asm volatile("" : "+v"(weff_o[i]));
    asm volatile("" : "+v"(brow));
    asm volatile("" : "+v"(be));

    float c = 0.0f;
    // two-step-ahead x registers: xa = x(t), xn = x(t+1)
    float xa[KX], xn[KX];
#pragma unroll
    for (int k = 0; k < KX; ++k) xa[k] = x[j * KX + k];          // x(0)
#pragma unroll
    for (int k = 0; k < KX; ++k) xn[k] = x[INP + j * KX + k];    // x(1)

    // pre-stage x_lds[0] = x(0) for wave0's step-0 x-dot
    if (wv == 1 && l < 8) {
        float4* xp = (float4*)&x_lds[0][j * KX];
        float4 v;
        v.x = xa[0];  v.y = xa[1];  v.z = xa[2];  v.w = xa[3];  xp[0] = v;
        v.x = xa[4];  v.y = xa[5];  v.z = xa[6];  v.w = xa[7];  xp[1] = v;
        v.x = xa[8];  v.y = xa[9];  v.z = xa[10]; v.w = xa[11]; xp[2] = v;
        v.x = xa[12]; v.y = xa[13]; v.z = xa[14]; v.w = xa[15]; xp[3] = v;
    }
    __syncthreads();   // one full-drain barrier before the loop

    bool dead = false;   // safety latch: never hang the device

    for (u32 t = 0; t <= T_SEQ; ++t) {
        if (t == T_SEQ && w != 0) break;   // only WG0 runs the tail iteration

        // ---- phase 1 (compute waves): x-dot from xa(t); rotate xa<-xn;
        //      prefetch xn <- x(t+2). The prefetch flies across both lgkm
        //      barriers; its wait lands at next step's rotation (2 steps of
        //      slack => no stall). Wave0 does nothing here (polls below). ----
        float xd0 = 0.0f, xd1 = 0.0f, xd2 = 0.0f, xd3 = 0.0f;
        if (wv != 0) {
#pragma unroll
            for (int k = 0; k < KX; k += 4) {
                xd0 += wi[k + 0] * xa[k + 0];
                xd1 += wi[k + 1] * xa[k + 1];
                xd2 += wi[k + 2] * xa[k + 2];
                xd3 += wi[k + 3] * xa[k + 3];
            }
#pragma unroll
            for (int k = 0; k < KX; ++k) xa[k] = xn[k];
            const int tn2 = (t + 2 < T_SEQ) ? (int)(t + 2) : (T_SEQ - 1);
#pragma unroll
            for (int k = 0; k < KX; k += 4) {
                const float4 x4 = *(const float4*)&x[tn2 * INP + j * KX + k];
                xn[k + 0] = x4.x; xn[k + 1] = x4.y;
                xn[k + 2] = x4.z; xn[k + 3] = x4.w;
            }
        }

        // ---- wave0: t=0 synthesizes h0=0; t>=1 polls the MALL rail (agent
        //      loads, 4 x 8B per lane, per-lane early-out, 8-bit tag).
        //      Wave0 issues NO other VMEM, so the poll's implicit vmcnt
        //      waits cover only these 4 loads. ----
        if (wv == 0 && !dead) {
            float2* HL = (float2*)h_lds[t & 1];
            if (t == 0) {
                float2 z; z.x = 0.0f; z.y = 0.0f;
                HL[l +   0] = z;
                HL[l +  64] = z;
                HL[l + 128] = z;
                HL[l + 192] = z;
            } else {
                const u64* P = hbuf + (t & 1) * NPK;
                const u32 tLo = t & 15u;
                const u32 tHi = (t >> 4) & 15u;
                bool mine = false;
                int guard = 0;
                while (true) {
                    if (!mine) {
                        u64 p0, p1, p2, p3;
                        p0 = __hip_atomic_load(P + l, __ATOMIC_RELAXED,
                                               __HIP_MEMORY_SCOPE_AGENT);
                        p1 = __hip_atomic_load(P + l + 64, __ATOMIC_RELAXED,
                                               __HIP_MEMORY_SCOPE_AGENT);
                        p2 = __hip_atomic_load(P + l + 128, __ATOMIC_RELAXED,
                                               __HIP_MEMORY_SCOPE_AGENT);
                        p3 = __hip_atomic_load(P + l + 192, __ATOMIC_RELAXED,
                                               __HIP_MEMORY_SCOPE_AGENT);
                        const bool ok =
                            ((((u32)p0 ^ tLo) & 15u) == 0u) &&
                            ((((u32)(p0 >> 32) ^ tHi) & 15u) == 0u) &&
                            ((((u32)p1 ^ tLo) & 15u) == 0u) &&
                            ((((u32)(p1 >> 32) ^ tHi) & 15u) == 0u) &&
                            ((((u32)p2 ^ tLo) & 15u) == 0u) &&
                            ((((u32)(p2 >> 32) ^ tHi) & 15u) == 0u) &&
                            ((((u32)p3 ^ tLo) & 15u) == 0u) &&
                            ((((u32)(p3 >> 32) ^ tHi) & 15u) == 0u);
                        if (ok) {
                            float2 h0, h1, h2, h3;
                            h0.x = __uint_as_float((u32)p0);
                            h0.y = __uint_as_float((u32)(p0 >> 32));
                            h1.x = __uint_as_float((u32)p1);
                            h1.y = __uint_as_float((u32)(p1 >> 32));
                            h2.x = __uint_as_float((u32)p2);
                            h2.y = __uint_as_float((u32)(p2 >> 32));
                            h3.x = __uint_as_float((u32)p3);
                            h3.y = __uint_as_float((u32)(p3 >> 32));
                            HL[l +   0] = h0;
                            HL[l +  64] = h1;
                            HL[l + 128] = h2;
                            HL[l + 192] = h3;
                            mine = true;
                        }
                    }
                    if (__ballot(mine) == ~0ull) break;
                    if (++guard > (1 << 22)) { dead = true; break; }  // no hang
                }
            }
        }

        wg_barrier_lgkm();   // barrier A — vmcnt NOT drained

        if (t < T_SEQ) {
            // ---- wave0: x-dot from LDS (never global; no vmcnt exposure) ----
            if (wv == 0) {
                const float4* xl4 = (const float4*)&x_lds[t & 1][j * KX];
                const float4 xv0 = xl4[0];
                const float4 xv1 = xl4[1];
                const float4 xv2 = xl4[2];
                const float4 xv3 = xl4[3];
                xd0 = wi[0] * xv0.x + wi[4] * xv1.x + wi[8]  * xv2.x + wi[12] * xv3.x;
                xd1 = wi[1] * xv0.y + wi[5] * xv1.y + wi[9]  * xv2.y + wi[13] * xv3.y;
                xd2 = wi[2] * xv0.z + wi[6] * xv1.z + wi[10] * xv2.z + wi[14] * xv3.z;
                xd3 = wi[3] * xv0.w + wi[7] * xv1.w + wi[11] * xv2.w + wi[15] * xv3.w;
            }

            float a0 = xd0, a1 = xd1, a2 = xd2, a3 = xd3;
            const float4* hl4 = (const float4*)&h_lds[t & 1][j * KW];
#pragma unroll
            for (int kk = 0; kk < 16; ++kk) {
                const int p = (kk + 2 * j) & 15;
                const float4 h4 = hl4[p];
                a0 += wr[4 * kk + 0] * h4.x;
                a1 += wr[4 * kk + 1] * h4.y;
                a2 += wr[4 * kk + 2] * h4.z;
                a3 += wr[4 * kk + 3] * h4.w;
            }
            // xor-butterfly over j: every lane holds its row's full sum
            float acc = (a0 + a1) + (a2 + a3);
            acc += __shfl_xor(acc, 1);
            acc += __shfl_xor(acc, 2);
            acc += __shfl_xor(acc, 4);
            acc += brow;
            // gates of element b live at rw = b, b+2, b+4, b+6 (valid l<16)
            const float ig = acc;
            const float fg = __shfl(acc, l + 16);
            const float gg = __shfl(acc, l + 32);
            const float og = __shfl(acc, l + 48);
            const float iv = fast_sigmoid(ig);
            const float fv = fast_sigmoid(fg);
            const float gv = fast_tanh(gg);
            const float ov = fast_sigmoid(og);
            c = fv * c + iv * gv;
            const float hv = ov * fast_tanh(c);
            // stage this wave's packet: 8-bit tag in-band — (t+1)&15 in
            // h_even low nibble, ((t+1)>>4)&15 in h_odd low nibble
            const float hv1 = __shfl(hv, 8);     // element b=1 (lane 8)
            if (l == 0) {
                const u32 b0  = (__float_as_uint(hv)  & ~15u) | ((t + 1) & 15u);
                const u32 b1v = (__float_as_uint(hv1) & ~15u) | (((t + 1) >> 4) & 15u);
                gather_lds[wv] = ((u64)b1v << 32) | (u64)b0;
            }
            // ---- wave1: stage x(t+1) row (xa after rotation; its load
            //      completed >=1.5 steps ago => the ds_write's vmcnt wait is
            //      counted, not a drain) ----
            if (wv == 1 && l < 8) {
                float4* xp = (float4*)&x_lds[(t + 1) & 1][j * KX];
                float4 v;
                v.x = xa[0];  v.y = xa[1];  v.z = xa[2];  v.w = xa[3];  xp[0] = v;
                v.x = xa[4];  v.y = xa[5];  v.z = xa[6];  v.w = xa[7];  xp[1] = v;
                v.x = xa[8];  v.y = xa[9];  v.z = xa[10]; v.w = xa[11]; xp[2] = v;
                v.x = xa[12]; v.y = xa[13]; v.z = xa[14]; v.w = xa[15]; xp[3] = v;
            }

            wg_barrier_lgkm();   // barrier B — packets + x row staged (lgkm)

            // ---- coalesced publish by a ROTATING compute wave (never the
            //      poller): lanes 0-7 store the WG's 64B packet line with
            //      agent-scope atomics (MALL). Issued before anyone's next
            //      poll; retires in background (counted waits, never drained
            //      by a barrier or by wave0's poll). ----
            const int mwv = 1 + (int)(t % 7u);
            if (wv == mwv && l < 8) {
                const u64 pkt = gather_lds[l];
                __hip_atomic_store(&hbuf[((t + 1) & 1) * NPK + w * 8 + l],
                                   pkt, __ATOMIC_RELAXED,
                                   __HIP_MEMORY_SCOPE_AGENT);
            }
        }

        // out[t-1] = dot(h_t, w_eff) + b_eff — WG0 wave2, after publish
        if (is_out && t >= 1) {
            float pd = 0.0f;
#pragma unroll
            for (int i = 0; i < 8; ++i)
                pd += h_lds[t & 1][l + 64 * i] * weff_o[i];
            pd += __shfl_xor(pd, 1);
            pd += __shfl_xor(pd, 2);
            pd += __shfl_xor(pd, 4);
            pd += __shfl_xor(pd, 8);
            pd += __shfl_xor(pd, 16);
            pd += __shfl_xor(pd, 32);
            if (l == 0) out[t - 1] = pd + be;
        }
    }
}

extern "C" void kernel_launch(void* const* d_in, const int* in_sizes, int n_in,
                              void* d_out, int out_size, void* d_ws, size_t ws_size,
                              hipStream_t stream)
{
    const float* x    = (const float*)d_in[0];
    const float* W_ih = (const float*)d_in[1];
    const float* W_hh = (const float*)d_in[2];
    const float* b_ih = (const float*)d_in[3];
    const float* b_hh = (const float*)d_in[4];
    const float* W1   = (const float*)d_in[5];
    const float* b1   = (const float*)d_in[6];
    const float* Wout = (const float*)d_in[7];
    float* out = (float*)d_out;

    u64* hbuf = (u64*)d_ws;    // 2 x 256 packets = 4 KB

    // zero packets (belt-and-braces; t=0 never reads the wire and the 8-bit
    // tag rejects stale generations anyway)
    hipMemsetAsync(d_ws, 0, 2 * NPK * sizeof(u64), stream);
    lstm_persist<<<NWG, NTH, 0, stream>>>(x, W_ih, W_hh, b_ih, b_hh, W1, b1,
                                          Wout, hbuf, out);
}